// Round 4
// baseline (241.283 us; speedup 1.0000x reference)
//
#include <hip/hip_runtime.h>
#include <hip/hip_bf16.h>
#include <math.h>

#define BN 2
#define NPTS 4096
#define DIM 64
#define HID 256
#define KNB 16
#define CAP 320

typedef __attribute__((ext_vector_type(8))) short bf16x8;
typedef __attribute__((ext_vector_type(4))) float f32x4;
#define MFMA16(a, b, c) __builtin_amdgcn_mfma_f32_16x16x32_bf16(a, b, c, 0, 0, 0)

__device__ __forceinline__ unsigned short f2bf(float f) {
  unsigned int u = __float_as_uint(f);
  unsigned int r = (u + 0x7fffu + ((u >> 16) & 1u)) >> 16;
  return (unsigned short)r;
}

// ---------------------------------------------------------------------------
// Kernel 0: pack w_a1/w_a2/w_p2 to bf16 in MFMA B-fragment lane order.
// ---------------------------------------------------------------------------
__global__ __launch_bounds__(256) void pack_kernel(
    const float* __restrict__ w_a1, const float* __restrict__ w_a2,
    const float* __restrict__ w_p2, unsigned short* __restrict__ pk1,
    unsigned short* __restrict__ pk2, unsigned short* __restrict__ pkp) {
  int e = blockIdx.x * 256 + threadIdx.x;
  if (e < 16384) {  // w_a1 [64][256]: KS=2, NT=16
    int j = e & 7, lane = (e >> 3) & 63, t = e >> 9;
    int ks = t & 1, nt = t >> 1;
    int k = ks * 32 + ((lane >> 4) << 3) + j, n = nt * 16 + (lane & 15);
    pk1[e] = f2bf(w_a1[k * 256 + n]);
  } else if (e < 32768) {  // w_a2 [256][64]: KS=8, NT=4
    int e2 = e - 16384;
    int j = e2 & 7, lane = (e2 >> 3) & 63, t = e2 >> 9;
    int ks = t & 7, nt = t >> 3;
    int k = ks * 32 + ((lane >> 4) << 3) + j, n = nt * 16 + (lane & 15);
    pk2[e2] = f2bf(w_a2[k * 64 + n]);
  } else if (e < 36864) {  // w_p2 [64][64]: KS=2, NT=4
    int e3 = e - 32768;
    int j = e3 & 7, lane = (e3 >> 3) & 63, t = e3 >> 9;
    int ks = t & 1, nt = t >> 1;
    int k = ks * 32 + ((lane >> 4) << 3) + j, n = nt * 16 + (lane & 15);
    pkp[e3] = f2bf(w_p2[k * 64 + n]);
  }
}

// ---------------------------------------------------------------------------
// Kernel 1: qkv = x @ w_qkv + b_qkv.   [8192,64] @ [64,192]
// ---------------------------------------------------------------------------
__global__ __launch_bounds__(256) void qkv_kernel(
    const float* __restrict__ x, const float* __restrict__ w,
    const float* __restrict__ b, float* __restrict__ qkv) {
  __shared__ float sw[64 * 192];   // 48 KB
  __shared__ float sx[32 * 64];    // 8 KB
  int tid = threadIdx.x;
  int row0 = blockIdx.x * 32;
  for (int o = tid; o < 64 * 192; o += 256) sw[o] = w[o];
  for (int o = tid; o < 32 * 64; o += 256) sx[o] = x[(size_t)row0 * 64 + o];
  __syncthreads();
  for (int o = tid; o < 32 * 192; o += 256) {
    int r = o / 192, c = o % 192;
    float acc = b[c];
    const float* xr = &sx[r * 64];
#pragma unroll
    for (int d = 0; d < 64; ++d) acc = fmaf(xr[d], sw[d * 192 + c], acc);
    qkv[(size_t)(row0 + r) * 192 + c] = acc;
  }
}

// ---------------------------------------------------------------------------
// Kernel 2 (v3): KNN top-16, 4 queries/block, no histogram atomics.
//   phase 1: d^2 -> LDS; 8 power-of-4 exponent buckets counted in per-thread
//            u64 registers (16-bit fields), fused into the distance loop.
//   phase 2: shfl-reduce counters; per query pick smallest threshold with
//            count >= 16 (t* = 4/4^j).
//   phase 3: collect d2 < t* (cap 320), exact rank select on (d2bits,idx).
//   fallback (pathological overflow): exact 16-round block argmin.
// ---------------------------------------------------------------------------
__global__ __launch_bounds__(256) void knn_kernel(
    const float* __restrict__ pos, int* __restrict__ knn) {
  __shared__ float s_d2[4][NPTS];                 // 64 KB
  __shared__ unsigned int cbits[4][CAP];          // 5 KB
  __shared__ int cidx[4][CAP];                    // 5 KB
  __shared__ unsigned long long wred[4][4][2];
  __shared__ float sthr[4];
  __shared__ unsigned int scnt[4];

  int tid = threadIdx.x, lane = tid & 63, wv = tid >> 6;
  int g0 = blockIdx.x * 4;        // first global point id (b*4096+i)
  int b = g0 >> 12;
  const float* posb = pos + (size_t)b * NPTS * 3;

  float qx[4], qy[4], qz[4];
#pragma unroll
  for (int q = 0; q < 4; ++q) {
    int i = (g0 + q) & (NPTS - 1);
    qx[q] = posb[i * 3 + 0];
    qy[q] = posb[i * 3 + 1];
    qz[q] = posb[i * 3 + 2];
  }
  if (tid < 4) scnt[tid] = 0;

  unsigned long long c0[4] = {0ull, 0ull, 0ull, 0ull};
  unsigned long long c1[4] = {0ull, 0ull, 0ull, 0ull};

  // phase 1: distances + fused bucket count
  for (int c = 0; c < NPTS / 256; ++c) {
    int j = c * 256 + tid;
    float px = posb[j * 3 + 0], py = posb[j * 3 + 1], pz = posb[j * 3 + 2];
#pragma unroll
    for (int q = 0; q < 4; ++q) {
      float dx = qx[q] - px, dy = qy[q] - py, dz = qz[q] - pz;
      float d2 = fmaf(dz, dz, fmaf(dy, dy, dx * dx));
      s_d2[q][j] = d2;
      // bucket j: d2 in [4/4^(j+1), 4/4^j), clamped to [0,7]
      int jb = (int)(128 - (int)(__float_as_uint(d2) >> 23)) >> 1;
      jb = jb < 0 ? 0 : (jb > 7 ? 7 : jb);
      unsigned long long amt = 1ull << ((jb & 3) << 4);
      bool lo = jb < 4;
      c0[q] += lo ? amt : 0ull;
      c1[q] += lo ? 0ull : amt;
    }
  }

  // phase 2: reduce counters, pick per-query threshold
#pragma unroll
  for (int q = 0; q < 4; ++q) {
#pragma unroll
    for (int off = 32; off > 0; off >>= 1) {
      c0[q] += __shfl_down(c0[q], off);
      c1[q] += __shfl_down(c1[q], off);
    }
    if (lane == 0) { wred[wv][q][0] = c0[q]; wred[wv][q][1] = c1[q]; }
  }
  __syncthreads();
  if (tid < 4) {
    int q = tid;
    unsigned long long t0 =
        wred[0][q][0] + wred[1][q][0] + wred[2][q][0] + wred[3][q][0];
    unsigned long long t1 =
        wred[0][q][1] + wred[1][q][1] + wred[2][q][1] + wred[3][q][1];
    unsigned int cnt[8];
#pragma unroll
    for (int f = 0; f < 4; ++f) {
      cnt[f] = (unsigned int)((t0 >> (16 * f)) & 0xFFFFu);
      cnt[4 + f] = (unsigned int)((t1 >> (16 * f)) & 0xFFFFu);
    }
    unsigned int cum = 0;
    int jstar = 0;
    for (int j = 7; j >= 0; --j) {
      cum += cnt[j];
      if (cum >= KNB) { jstar = j; break; }
    }
    // t* = 2^(2-2*jstar): float bits = (129 - 2j) << 23
    sthr[q] = __int_as_float((129 - 2 * jstar) << 23);
  }
  __syncthreads();

  // phase 3: collect candidates
  float t0r = sthr[0], t1r = sthr[1], t2r = sthr[2], t3r = sthr[3];
  float tq[4] = {t0r, t1r, t2r, t3r};
  for (int c = 0; c < NPTS / 256; ++c) {
    int j = c * 256 + tid;
#pragma unroll
    for (int q = 0; q < 4; ++q) {
      float d2 = s_d2[q][j];
      if (d2 < tq[q]) {
        unsigned int p = atomicAdd(&scnt[q], 1u);
        if (p < CAP) {
          cbits[q][p] = __float_as_uint(d2);
          cidx[q][p] = j;
        }
      }
    }
  }
  __syncthreads();

  // rank selection: wave wv handles query wv
  {
    int q = wv;
    int L = (int)scnt[q];
    if (L <= CAP) {
      for (int i = lane; i < L; i += 64) {
        unsigned long long ki =
            ((unsigned long long)cbits[q][i] << 32) | (unsigned int)cidx[q][i];
        int rank = 0;
        for (int m = 0; m < L; ++m) {
          unsigned long long km = ((unsigned long long)cbits[q][m] << 32) |
                                  (unsigned int)cidx[q][m];
          rank += km < ki;
        }
        if (rank < KNB) knn[(size_t)(g0 + q) * KNB + rank] = cidx[q][i];
      }
    }
  }
  __syncthreads();

  // exact fallback for overflow (pathological; uniform branch per query)
  for (int q = 0; q < 4; ++q) {
    if (scnt[q] > CAP) {
      for (int r = 0; r < KNB; ++r) {
        unsigned long long best = ~0ull;
        for (int c = 0; c < NPTS / 256; ++c) {
          int j = c * 256 + tid;
          unsigned long long key =
              ((unsigned long long)__float_as_uint(s_d2[q][j]) << 32) |
              (unsigned int)j;
          best = best < key ? best : key;
        }
#pragma unroll
        for (int off = 32; off > 0; off >>= 1) {
          unsigned long long o = __shfl_down(best, off);
          best = best < o ? best : o;
        }
        if (lane == 0) wred[wv][0][0] = best;
        __syncthreads();
        if (tid == 0) {
          unsigned long long m0 = wred[0][0][0], m1 = wred[1][0][0];
          unsigned long long m2 = wred[2][0][0], m3 = wred[3][0][0];
          unsigned long long a = m0 < m1 ? m0 : m1;
          unsigned long long d = m2 < m3 ? m2 : m3;
          a = a < d ? a : d;
          int j = (int)(unsigned int)a;
          knn[(size_t)(g0 + q) * KNB + r] = j;
          s_d2[q][j] = __int_as_float(0x7f000000);
        }
        __syncthreads();
      }
    }
  }
}

// ---------------------------------------------------------------------------
// Kernel 3: MFMA attention (unchanged from R3).
// ---------------------------------------------------------------------------
__global__ __launch_bounds__(256) void attn_kernel(
    const float* __restrict__ qkv, const float* __restrict__ pos,
    const int* __restrict__ knn, const unsigned short* __restrict__ pk1,
    const unsigned short* __restrict__ pk2,
    const unsigned short* __restrict__ pkp, const float* __restrict__ w_p1,
    const float* __restrict__ b_p1, const float* __restrict__ b_p2,
    const float* __restrict__ b_a1, const float* __restrict__ b_a2,
    float* __restrict__ aggout) {
  __shared__ __align__(16) char region[33792];
  __shared__ __align__(16) unsigned short s_h[64][72];
  __shared__ float s_v[64][64];
  __shared__ int s_idx[64];

  float(*s_qk)[66] = (float(*)[66])region;
  unsigned short(*s_e)[72] = (unsigned short(*)[72])(region + 16896);
  unsigned short(*s_t)[264] = (unsigned short(*)[264])region;
  float(*s_sc)[66] = (float(*)[66])region;

  int tid = threadIdx.x, w = tid >> 6, lane = tid & 63;
  int g0 = blockIdx.x * 4;
  int b = g0 >> 12;

  if (tid < 64) {
    int p = tid >> 4, k = tid & 15;
    s_idx[tid] = knn[(size_t)(g0 + p) * KNB + k];
  }
  __syncthreads();

  for (int it = 0; it < 16; ++it) {
    int r = it * 4 + w;
    int g = g0 + (r >> 4);
    int jb = (b << 12) | s_idx[r];
    float qv = qkv[(size_t)g * 192 + lane];
    float kv = qkv[(size_t)jb * 192 + 64 + lane];
    float vv = qkv[(size_t)jb * 192 + 128 + lane];
    s_qk[r][lane] = qv - kv;
    s_v[r][lane] = vv;
  }
  {
    float w0 = w_p1[lane], w1 = w_p1[64 + lane], w2 = w_p1[128 + lane];
    float bp = b_p1[lane];
    for (int it = 0; it < 16; ++it) {
      int r = it * 4 + w;
      int g = g0 + (r >> 4);
      int jb = (b << 12) | s_idx[r];
      float rx = pos[(size_t)g * 3 + 0] - pos[(size_t)jb * 3 + 0];
      float ry = pos[(size_t)g * 3 + 1] - pos[(size_t)jb * 3 + 1];
      float rz = pos[(size_t)g * 3 + 2] - pos[(size_t)jb * 3 + 2];
      float e = fmaf(rz, w2, fmaf(ry, w1, fmaf(rx, w0, bp)));
      s_e[r][lane] = f2bf(fmaxf(e, 0.f));
    }
  }
  __syncthreads();

  int m = lane & 15, quad = lane >> 4;
  {
    bf16x8 a0 = *(const bf16x8*)&s_e[16 * w + m][quad * 8];
    bf16x8 a1 = *(const bf16x8*)&s_e[16 * w + m][32 + quad * 8];
#pragma unroll
    for (int nt = 0; nt < 4; ++nt) {
      bf16x8 b0 = *(const bf16x8*)(pkp + ((size_t)(nt * 2 + 0) * 64 + lane) * 8);
      bf16x8 b1 = *(const bf16x8*)(pkp + ((size_t)(nt * 2 + 1) * 64 + lane) * 8);
      f32x4 acc = {0.f, 0.f, 0.f, 0.f};
      acc = MFMA16(a0, b0, acc);
      acc = MFMA16(a1, b1, acc);
      int col = nt * 16 + m;
      float bp2 = b_p2[col];
#pragma unroll
      for (int i = 0; i < 4; ++i) {
        int row = 16 * w + quad * 4 + i;
        float h = s_qk[row][col] + acc[i] + bp2;
        s_h[row][col] = f2bf(h);
      }
    }
  }
  __syncthreads();

  {
    bf16x8 a0 = *(const bf16x8*)&s_h[16 * w + m][quad * 8];
    bf16x8 a1 = *(const bf16x8*)&s_h[16 * w + m][32 + quad * 8];
#pragma unroll 4
    for (int nt = 0; nt < 16; ++nt) {
      bf16x8 b0 = *(const bf16x8*)(pk1 + ((size_t)(nt * 2 + 0) * 64 + lane) * 8);
      bf16x8 b1 = *(const bf16x8*)(pk1 + ((size_t)(nt * 2 + 1) * 64 + lane) * 8);
      f32x4 acc = {0.f, 0.f, 0.f, 0.f};
      acc = MFMA16(a0, b0, acc);
      acc = MFMA16(a1, b1, acc);
      int col = nt * 16 + m;
      float ba = b_a1[col];
#pragma unroll
      for (int i = 0; i < 4; ++i) {
        int row = 16 * w + quad * 4 + i;
        s_t[row][col] = f2bf(fmaxf(acc[i] + ba, 0.f));
      }
    }
  }

  f32x4 acc2[4];
#pragma unroll
  for (int nt = 0; nt < 4; ++nt) acc2[nt] = (f32x4){0.f, 0.f, 0.f, 0.f};
#pragma unroll
  for (int ks = 0; ks < 8; ++ks) {
    bf16x8 a = *(const bf16x8*)&s_t[16 * w + m][ks * 32 + quad * 8];
#pragma unroll
    for (int nt = 0; nt < 4; ++nt) {
      bf16x8 bb = *(const bf16x8*)(pk2 + ((size_t)(nt * 8 + ks) * 64 + lane) * 8);
      acc2[nt] = MFMA16(a, bb, acc2[nt]);
    }
  }
  __syncthreads();
#pragma unroll
  for (int nt = 0; nt < 4; ++nt) {
    int col = nt * 16 + m;
    float ba2 = b_a2[col];
#pragma unroll
    for (int i = 0; i < 4; ++i)
      s_sc[16 * w + quad * 4 + i][col] = acc2[nt][i] + ba2;
  }
  __syncthreads();

  {
    int p = w, d = lane;
    float mx = -1e30f;
#pragma unroll
    for (int k = 0; k < 16; ++k) mx = fmaxf(mx, s_sc[p * 16 + k][d]);
    float s = 0.f, a = 0.f;
#pragma unroll
    for (int k = 0; k < 16; ++k) {
      float e = expf(s_sc[p * 16 + k][d] - mx);
      s += e;
      a = fmaf(e, s_v[p * 16 + k][d], a);
    }
    aggout[(size_t)(g0 + p) * 64 + d] = a / s;
  }
}

// ---------------------------------------------------------------------------
// Kernel 4: y = agg @ w_fc + b_fc; accumulate per-channel sum/sumsq.
// ---------------------------------------------------------------------------
__global__ __launch_bounds__(256) void fc_kernel(
    const float* __restrict__ agg, const float* __restrict__ w_fc,
    const float* __restrict__ b_fc, float* __restrict__ y,
    float* __restrict__ stats) {
  __shared__ float sw[64 * 64];
  __shared__ float sa[64 * 64];
  __shared__ float red[4][64];
  __shared__ float red2[4][64];
  int tid = threadIdx.x;
  int r0 = blockIdx.x * 64;
  for (int o = tid; o < 4096; o += 256) sw[o] = w_fc[o];
  for (int o = tid; o < 4096; o += 256) sa[o] = agg[(size_t)r0 * 64 + o];
  __syncthreads();
  int c = tid & 63, g = tid >> 6;
  float psum = 0.f, psq = 0.f;
  for (int rr = g; rr < 64; rr += 4) {
    float acc = b_fc[c];
#pragma unroll
    for (int d = 0; d < 64; ++d) acc = fmaf(sa[rr * 64 + d], sw[d * 64 + c], acc);
    y[(size_t)(r0 + rr) * 64 + c] = acc;
    psum += acc;
    psq = fmaf(acc, acc, psq);
  }
  red[g][c] = psum;
  red2[g][c] = psq;
  __syncthreads();
  if (tid < 64) {
    float s = red[0][tid] + red[1][tid] + red[2][tid] + red[3][tid];
    float s2 = red2[0][tid] + red2[1][tid] + red2[2][tid] + red2[3][tid];
    atomicAdd(&stats[tid], s);
    atomicAdd(&stats[64 + tid], s2);
  }
}

// ---------------------------------------------------------------------------
// Kernel 5: BN (batch stats) + relu + residual.
// ---------------------------------------------------------------------------
__global__ __launch_bounds__(256) void bn_kernel(
    const float* __restrict__ y, const float* __restrict__ x,
    const float* __restrict__ stats, const float* __restrict__ gamma,
    const float* __restrict__ beta, float* __restrict__ out) {
  size_t o = (size_t)blockIdx.x * 256 + threadIdx.x;
  int c = (int)(o & 63);
  const float inv_n = 1.f / 8192.f;
  float mean = stats[c] * inv_n;
  float var = stats[64 + c] * inv_n - mean * mean;
  float inv = rsqrtf(var + 1e-5f);
  float v = (y[o] - mean) * inv * gamma[c] + beta[c];
  out[o] = fmaxf(v, 0.f) + x[o];
}

// ---------------------------------------------------------------------------
extern "C" void kernel_launch(void* const* d_in, const int* in_sizes, int n_in,
                              void* d_out, int out_size, void* d_ws,
                              size_t ws_size, hipStream_t stream) {
  const float* x = (const float*)d_in[0];
  const float* pos = (const float*)d_in[1];
  const float* w_qkv = (const float*)d_in[2];
  const float* b_qkv = (const float*)d_in[3];
  const float* w_p1 = (const float*)d_in[4];
  const float* b_p1 = (const float*)d_in[5];
  const float* w_p2 = (const float*)d_in[6];
  const float* b_p2 = (const float*)d_in[7];
  const float* w_a1 = (const float*)d_in[8];
  const float* b_a1 = (const float*)d_in[9];
  const float* w_a2 = (const float*)d_in[10];
  const float* b_a2 = (const float*)d_in[11];
  const float* w_fc = (const float*)d_in[12];
  const float* b_fc = (const float*)d_in[13];
  const float* gamma = (const float*)d_in[14];
  const float* beta = (const float*)d_in[15];

  char* ws = (char*)d_ws;
  float* qkv = (float*)(ws + 0);                        // 6291456 B
  int* knn = (int*)(ws + 6291456);                      // 524288 B
  float* agg = (float*)(ws + 6815744);                  // 2097152 B
  float* y = (float*)(ws + 8912896);                    // 2097152 B
  float* stats = (float*)(ws + 11010048);               // 512 B
  unsigned short* pk1 = (unsigned short*)(ws + 11010560);  // 32768 B
  unsigned short* pk2 = (unsigned short*)(ws + 11043328);  // 32768 B
  unsigned short* pkp = (unsigned short*)(ws + 11076096);  // 8192 B

  hipMemsetAsync(stats, 0, 512, stream);
  hipLaunchKernelGGL(pack_kernel, dim3(144), dim3(256), 0, stream, w_a1, w_a2,
                     w_p2, pk1, pk2, pkp);
  hipLaunchKernelGGL(qkv_kernel, dim3(256), dim3(256), 0, stream, x, w_qkv,
                     b_qkv, qkv);
  hipLaunchKernelGGL(knn_kernel, dim3(2048), dim3(256), 0, stream, pos, knn);
  hipLaunchKernelGGL(attn_kernel, dim3(2048), dim3(256), 0, stream, qkv, pos,
                     knn, pk1, pk2, pkp, w_p1, b_p1, b_p2, b_a1, b_a2, agg);
  hipLaunchKernelGGL(fc_kernel, dim3(128), dim3(256), 0, stream, agg, w_fc,
                     b_fc, y, stats);
  hipLaunchKernelGGL(bn_kernel, dim3(2048), dim3(256), 0, stream, y, x, stats,
                     gamma, beta, (float*)d_out);
}

// Round 5
// 222.973 us; speedup vs baseline: 1.0821x; 1.0821x over previous
//
#include <hip/hip_runtime.h>
#include <hip/hip_bf16.h>
#include <math.h>

#define BN 2
#define NPTS 4096
#define DIM 64
#define HID 256
#define KNB 16
#define CAP 384

typedef __attribute__((ext_vector_type(8))) short bf16x8;
typedef __attribute__((ext_vector_type(4))) float f32x4;
#define MFMA16(a, b, c) __builtin_amdgcn_mfma_f32_16x16x32_bf16(a, b, c, 0, 0, 0)

__device__ __forceinline__ unsigned short f2bf(float f) {
  unsigned int u = __float_as_uint(f);
  unsigned int r = (u + 0x7fffu + ((u >> 16) & 1u)) >> 16;
  return (unsigned short)r;
}

// ---------------------------------------------------------------------------
// Kernel 0: pack w_a1/w_a2/w_p2 to bf16 in MFMA B-fragment lane order.
// ---------------------------------------------------------------------------
__global__ __launch_bounds__(256) void pack_kernel(
    const float* __restrict__ w_a1, const float* __restrict__ w_a2,
    const float* __restrict__ w_p2, unsigned short* __restrict__ pk1,
    unsigned short* __restrict__ pk2, unsigned short* __restrict__ pkp) {
  int e = blockIdx.x * 256 + threadIdx.x;
  if (e < 16384) {  // w_a1 [64][256]: KS=2, NT=16
    int j = e & 7, lane = (e >> 3) & 63, t = e >> 9;
    int ks = t & 1, nt = t >> 1;
    int k = ks * 32 + ((lane >> 4) << 3) + j, n = nt * 16 + (lane & 15);
    pk1[e] = f2bf(w_a1[k * 256 + n]);
  } else if (e < 32768) {  // w_a2 [256][64]: KS=8, NT=4
    int e2 = e - 16384;
    int j = e2 & 7, lane = (e2 >> 3) & 63, t = e2 >> 9;
    int ks = t & 7, nt = t >> 3;
    int k = ks * 32 + ((lane >> 4) << 3) + j, n = nt * 16 + (lane & 15);
    pk2[e2] = f2bf(w_a2[k * 64 + n]);
  } else if (e < 36864) {  // w_p2 [64][64]: KS=2, NT=4
    int e3 = e - 32768;
    int j = e3 & 7, lane = (e3 >> 3) & 63, t = e3 >> 9;
    int ks = t & 1, nt = t >> 1;
    int k = ks * 32 + ((lane >> 4) << 3) + j, n = nt * 16 + (lane & 15);
    pkp[e3] = f2bf(w_p2[k * 64 + n]);
  }
}

// ---------------------------------------------------------------------------
// Kernel 1: qkv = x @ w_qkv + b_qkv.   [8192,64] @ [64,192]
// ---------------------------------------------------------------------------
__global__ __launch_bounds__(256) void qkv_kernel(
    const float* __restrict__ x, const float* __restrict__ w,
    const float* __restrict__ b, float* __restrict__ qkv) {
  __shared__ float sw[64 * 192];   // 48 KB
  __shared__ float sx[32 * 64];    // 8 KB
  int tid = threadIdx.x;
  int row0 = blockIdx.x * 32;
  for (int o = tid; o < 64 * 192; o += 256) sw[o] = w[o];
  for (int o = tid; o < 32 * 64; o += 256) sx[o] = x[(size_t)row0 * 64 + o];
  __syncthreads();
  for (int o = tid; o < 32 * 192; o += 256) {
    int r = o / 192, c = o % 192;
    float acc = b[c];
    const float* xr = &sx[r * 64];
#pragma unroll
    for (int d = 0; d < 64; ++d) acc = fmaf(xr[d], sw[d * 192 + c], acc);
    qkv[(size_t)(row0 + r) * 192 + c] = acc;
  }
}

// ---------------------------------------------------------------------------
// Kernel 2 (v4): KNN top-16, 4 queries/block, two-pass recompute (no d2
// storage -> LDS ~12.6 KB, was 74.5 KB which capped occupancy at 2 blk/CU).
//   pass 1: d^2 bucket-count in per-thread u64 registers (16-bit fields).
//   select: shfl-reduce; per query smallest power-of-4 threshold w/ cnt>=16.
//   pass 2: recompute d^2 (identical fmaf chain), collect < t* (cap 384).
//   rank select on (d2bits, idx) = reference (dist, idx) tie-break.
//   fallback (overflow, ~impossible): iterative min-key-above-prev argmin.
// ---------------------------------------------------------------------------
__global__ __launch_bounds__(256) void knn_kernel(
    const float* __restrict__ pos, int* __restrict__ knn) {
  __shared__ unsigned int cbits[4][CAP];          // 6 KB
  __shared__ int cidx[4][CAP];                    // 6 KB
  __shared__ unsigned long long wred[4][4][2];
  __shared__ float sthr[4];
  __shared__ unsigned int scnt[4];
  __shared__ unsigned long long sprev;

  int tid = threadIdx.x, lane = tid & 63, wv = tid >> 6;
  int g0 = blockIdx.x * 4;        // first global point id (b*4096+i)
  int b = g0 >> 12;
  const float* posb = pos + (size_t)b * NPTS * 3;

  float qx[4], qy[4], qz[4];
#pragma unroll
  for (int q = 0; q < 4; ++q) {
    int i = (g0 + q) & (NPTS - 1);
    qx[q] = posb[i * 3 + 0];
    qy[q] = posb[i * 3 + 1];
    qz[q] = posb[i * 3 + 2];
  }
  if (tid < 4) scnt[tid] = 0;

  unsigned long long c0[4] = {0ull, 0ull, 0ull, 0ull};
  unsigned long long c1[4] = {0ull, 0ull, 0ull, 0ull};

  // pass 1: distances + fused bucket count (bucket j: d2 in [4^-j, 4*4^-j))
  for (int c = 0; c < NPTS / 256; ++c) {
    int j = c * 256 + tid;
    float px = posb[j * 3 + 0], py = posb[j * 3 + 1], pz = posb[j * 3 + 2];
#pragma unroll
    for (int q = 0; q < 4; ++q) {
      float dx = qx[q] - px, dy = qy[q] - py, dz = qz[q] - pz;
      float d2 = fmaf(dz, dz, fmaf(dy, dy, dx * dx));
      int jb = (int)(128 - (int)(__float_as_uint(d2) >> 23)) >> 1;
      jb = jb < 0 ? 0 : (jb > 7 ? 7 : jb);
      unsigned long long amt = 1ull << ((jb & 3) << 4);
      bool lo = jb < 4;
      c0[q] += lo ? amt : 0ull;
      c1[q] += lo ? 0ull : amt;
    }
  }

  // reduce counters, pick per-query threshold
#pragma unroll
  for (int q = 0; q < 4; ++q) {
#pragma unroll
    for (int off = 32; off > 0; off >>= 1) {
      c0[q] += __shfl_down(c0[q], off);
      c1[q] += __shfl_down(c1[q], off);
    }
    if (lane == 0) { wred[wv][q][0] = c0[q]; wred[wv][q][1] = c1[q]; }
  }
  __syncthreads();
  if (tid < 4) {
    int q = tid;
    unsigned long long t0 =
        wred[0][q][0] + wred[1][q][0] + wred[2][q][0] + wred[3][q][0];
    unsigned long long t1 =
        wred[0][q][1] + wred[1][q][1] + wred[2][q][1] + wred[3][q][1];
    unsigned int cnt[8];
#pragma unroll
    for (int f = 0; f < 4; ++f) {
      cnt[f] = (unsigned int)((t0 >> (16 * f)) & 0xFFFFu);
      cnt[4 + f] = (unsigned int)((t1 >> (16 * f)) & 0xFFFFu);
    }
    unsigned int cum = 0;
    int jstar = 0;
    for (int j = 7; j >= 0; --j) {
      cum += cnt[j];
      if (cum >= KNB) { jstar = j; break; }
    }
    // t* = 4*4^-jstar: float bits = (129 - 2j) << 23
    sthr[q] = __int_as_float((129 - 2 * jstar) << 23);
  }
  __syncthreads();

  // pass 2: recompute d2, collect candidates
  float tq[4] = {sthr[0], sthr[1], sthr[2], sthr[3]};
  for (int c = 0; c < NPTS / 256; ++c) {
    int j = c * 256 + tid;
    float px = posb[j * 3 + 0], py = posb[j * 3 + 1], pz = posb[j * 3 + 2];
#pragma unroll
    for (int q = 0; q < 4; ++q) {
      float dx = qx[q] - px, dy = qy[q] - py, dz = qz[q] - pz;
      float d2 = fmaf(dz, dz, fmaf(dy, dy, dx * dx));
      if (d2 < tq[q]) {
        unsigned int p = atomicAdd(&scnt[q], 1u);
        if (p < CAP) {
          cbits[q][p] = __float_as_uint(d2);
          cidx[q][p] = j;
        }
      }
    }
  }
  __syncthreads();

  // rank selection: wave wv handles query wv
  {
    int q = wv;
    int L = (int)scnt[q];
    if (L <= CAP) {
      for (int i = lane; i < L; i += 64) {
        unsigned long long ki =
            ((unsigned long long)cbits[q][i] << 32) | (unsigned int)cidx[q][i];
        int rank = 0;
        for (int m = 0; m < L; ++m) {
          unsigned long long km = ((unsigned long long)cbits[q][m] << 32) |
                                  (unsigned int)cidx[q][m];
          rank += km < ki;
        }
        if (rank < KNB) knn[(size_t)(g0 + q) * KNB + rank] = cidx[q][i];
      }
    }
  }
  __syncthreads();

  // exact fallback for overflow (block-uniform branch; keys strictly ascend)
  for (int q = 0; q < 4; ++q) {
    if (scnt[q] > CAP) {
      unsigned long long prev = 0ull;
      for (int r = 0; r < KNB; ++r) {
        unsigned long long best = ~0ull;
        for (int c = 0; c < NPTS / 256; ++c) {
          int j = c * 256 + tid;
          float dx = qx[q] - posb[j * 3 + 0];
          float dy = qy[q] - posb[j * 3 + 1];
          float dz = qz[q] - posb[j * 3 + 2];
          float d2 = fmaf(dz, dz, fmaf(dy, dy, dx * dx));
          unsigned long long key =
              ((unsigned long long)__float_as_uint(d2) << 32) | (unsigned int)j;
          bool ok = (r == 0) || (key > prev);
          best = (ok && key < best) ? key : best;
        }
#pragma unroll
        for (int off = 32; off > 0; off >>= 1) {
          unsigned long long o = __shfl_down(best, off);
          best = best < o ? best : o;
        }
        if (lane == 0) wred[wv][0][0] = best;
        __syncthreads();
        if (tid == 0) {
          unsigned long long m0 = wred[0][0][0], m1 = wred[1][0][0];
          unsigned long long m2 = wred[2][0][0], m3 = wred[3][0][0];
          unsigned long long a = m0 < m1 ? m0 : m1;
          unsigned long long d = m2 < m3 ? m2 : m3;
          a = a < d ? a : d;
          knn[(size_t)(g0 + q) * KNB + r] = (int)(unsigned int)a;
          sprev = a;
        }
        __syncthreads();
        prev = sprev;
        __syncthreads();
      }
    }
  }
}

// ---------------------------------------------------------------------------
// Kernel 3: MFMA attention (unchanged from R3/R4).
// ---------------------------------------------------------------------------
__global__ __launch_bounds__(256) void attn_kernel(
    const float* __restrict__ qkv, const float* __restrict__ pos,
    const int* __restrict__ knn, const unsigned short* __restrict__ pk1,
    const unsigned short* __restrict__ pk2,
    const unsigned short* __restrict__ pkp, const float* __restrict__ w_p1,
    const float* __restrict__ b_p1, const float* __restrict__ b_p2,
    const float* __restrict__ b_a1, const float* __restrict__ b_a2,
    float* __restrict__ aggout) {
  __shared__ __align__(16) char region[33792];
  __shared__ __align__(16) unsigned short s_h[64][72];
  __shared__ float s_v[64][64];
  __shared__ int s_idx[64];

  float(*s_qk)[66] = (float(*)[66])region;
  unsigned short(*s_e)[72] = (unsigned short(*)[72])(region + 16896);
  unsigned short(*s_t)[264] = (unsigned short(*)[264])region;
  float(*s_sc)[66] = (float(*)[66])region;

  int tid = threadIdx.x, w = tid >> 6, lane = tid & 63;
  int g0 = blockIdx.x * 4;
  int b = g0 >> 12;

  if (tid < 64) {
    int p = tid >> 4, k = tid & 15;
    s_idx[tid] = knn[(size_t)(g0 + p) * KNB + k];
  }
  __syncthreads();

  for (int it = 0; it < 16; ++it) {
    int r = it * 4 + w;
    int g = g0 + (r >> 4);
    int jb = (b << 12) | s_idx[r];
    float qv = qkv[(size_t)g * 192 + lane];
    float kv = qkv[(size_t)jb * 192 + 64 + lane];
    float vv = qkv[(size_t)jb * 192 + 128 + lane];
    s_qk[r][lane] = qv - kv;
    s_v[r][lane] = vv;
  }
  {
    float w0 = w_p1[lane], w1 = w_p1[64 + lane], w2 = w_p1[128 + lane];
    float bp = b_p1[lane];
    for (int it = 0; it < 16; ++it) {
      int r = it * 4 + w;
      int g = g0 + (r >> 4);
      int jb = (b << 12) | s_idx[r];
      float rx = pos[(size_t)g * 3 + 0] - pos[(size_t)jb * 3 + 0];
      float ry = pos[(size_t)g * 3 + 1] - pos[(size_t)jb * 3 + 1];
      float rz = pos[(size_t)g * 3 + 2] - pos[(size_t)jb * 3 + 2];
      float e = fmaf(rz, w2, fmaf(ry, w1, fmaf(rx, w0, bp)));
      s_e[r][lane] = f2bf(fmaxf(e, 0.f));
    }
  }
  __syncthreads();

  int m = lane & 15, quad = lane >> 4;
  {
    bf16x8 a0 = *(const bf16x8*)&s_e[16 * w + m][quad * 8];
    bf16x8 a1 = *(const bf16x8*)&s_e[16 * w + m][32 + quad * 8];
#pragma unroll
    for (int nt = 0; nt < 4; ++nt) {
      bf16x8 b0 = *(const bf16x8*)(pkp + ((size_t)(nt * 2 + 0) * 64 + lane) * 8);
      bf16x8 b1 = *(const bf16x8*)(pkp + ((size_t)(nt * 2 + 1) * 64 + lane) * 8);
      f32x4 acc = {0.f, 0.f, 0.f, 0.f};
      acc = MFMA16(a0, b0, acc);
      acc = MFMA16(a1, b1, acc);
      int col = nt * 16 + m;
      float bp2 = b_p2[col];
#pragma unroll
      for (int i = 0; i < 4; ++i) {
        int row = 16 * w + quad * 4 + i;
        float h = s_qk[row][col] + acc[i] + bp2;
        s_h[row][col] = f2bf(h);
      }
    }
  }
  __syncthreads();

  {
    bf16x8 a0 = *(const bf16x8*)&s_h[16 * w + m][quad * 8];
    bf16x8 a1 = *(const bf16x8*)&s_h[16 * w + m][32 + quad * 8];
#pragma unroll 4
    for (int nt = 0; nt < 16; ++nt) {
      bf16x8 b0 = *(const bf16x8*)(pk1 + ((size_t)(nt * 2 + 0) * 64 + lane) * 8);
      bf16x8 b1 = *(const bf16x8*)(pk1 + ((size_t)(nt * 2 + 1) * 64 + lane) * 8);
      f32x4 acc = {0.f, 0.f, 0.f, 0.f};
      acc = MFMA16(a0, b0, acc);
      acc = MFMA16(a1, b1, acc);
      int col = nt * 16 + m;
      float ba = b_a1[col];
#pragma unroll
      for (int i = 0; i < 4; ++i) {
        int row = 16 * w + quad * 4 + i;
        s_t[row][col] = f2bf(fmaxf(acc[i] + ba, 0.f));
      }
    }
  }

  f32x4 acc2[4];
#pragma unroll
  for (int nt = 0; nt < 4; ++nt) acc2[nt] = (f32x4){0.f, 0.f, 0.f, 0.f};
#pragma unroll
  for (int ks = 0; ks < 8; ++ks) {
    bf16x8 a = *(const bf16x8*)&s_t[16 * w + m][ks * 32 + quad * 8];
#pragma unroll
    for (int nt = 0; nt < 4; ++nt) {
      bf16x8 bb = *(const bf16x8*)(pk2 + ((size_t)(nt * 8 + ks) * 64 + lane) * 8);
      acc2[nt] = MFMA16(a, bb, acc2[nt]);
    }
  }
  __syncthreads();
#pragma unroll
  for (int nt = 0; nt < 4; ++nt) {
    int col = nt * 16 + m;
    float ba2 = b_a2[col];
#pragma unroll
    for (int i = 0; i < 4; ++i)
      s_sc[16 * w + quad * 4 + i][col] = acc2[nt][i] + ba2;
  }
  __syncthreads();

  {
    int p = w, d = lane;
    float mx = -1e30f;
#pragma unroll
    for (int k = 0; k < 16; ++k) mx = fmaxf(mx, s_sc[p * 16 + k][d]);
    float s = 0.f, a = 0.f;
#pragma unroll
    for (int k = 0; k < 16; ++k) {
      float e = expf(s_sc[p * 16 + k][d] - mx);
      s += e;
      a = fmaf(e, s_v[p * 16 + k][d], a);
    }
    aggout[(size_t)(g0 + p) * 64 + d] = a / s;
  }
}

// ---------------------------------------------------------------------------
// Kernel 4: y = agg @ w_fc + b_fc; accumulate per-channel sum/sumsq.
// ---------------------------------------------------------------------------
__global__ __launch_bounds__(256) void fc_kernel(
    const float* __restrict__ agg, const float* __restrict__ w_fc,
    const float* __restrict__ b_fc, float* __restrict__ y,
    float* __restrict__ stats) {
  __shared__ float sw[64 * 64];
  __shared__ float sa[64 * 64];
  __shared__ float red[4][64];
  __shared__ float red2[4][64];
  int tid = threadIdx.x;
  int r0 = blockIdx.x * 64;
  for (int o = tid; o < 4096; o += 256) sw[o] = w_fc[o];
  for (int o = tid; o < 4096; o += 256) sa[o] = agg[(size_t)r0 * 64 + o];
  __syncthreads();
  int c = tid & 63, g = tid >> 6;
  float psum = 0.f, psq = 0.f;
  for (int rr = g; rr < 64; rr += 4) {
    float acc = b_fc[c];
#pragma unroll
    for (int d = 0; d < 64; ++d) acc = fmaf(sa[rr * 64 + d], sw[d * 64 + c], acc);
    y[(size_t)(r0 + rr) * 64 + c] = acc;
    psum += acc;
    psq = fmaf(acc, acc, psq);
  }
  red[g][c] = psum;
  red2[g][c] = psq;
  __syncthreads();
  if (tid < 64) {
    float s = red[0][tid] + red[1][tid] + red[2][tid] + red[3][tid];
    float s2 = red2[0][tid] + red2[1][tid] + red2[2][tid] + red2[3][tid];
    atomicAdd(&stats[tid], s);
    atomicAdd(&stats[64 + tid], s2);
  }
}

// ---------------------------------------------------------------------------
// Kernel 5: BN (batch stats) + relu + residual.
// ---------------------------------------------------------------------------
__global__ __launch_bounds__(256) void bn_kernel(
    const float* __restrict__ y, const float* __restrict__ x,
    const float* __restrict__ stats, const float* __restrict__ gamma,
    const float* __restrict__ beta, float* __restrict__ out) {
  size_t o = (size_t)blockIdx.x * 256 + threadIdx.x;
  int c = (int)(o & 63);
  const float inv_n = 1.f / 8192.f;
  float mean = stats[c] * inv_n;
  float var = stats[64 + c] * inv_n - mean * mean;
  float inv = rsqrtf(var + 1e-5f);
  float v = (y[o] - mean) * inv * gamma[c] + beta[c];
  out[o] = fmaxf(v, 0.f) + x[o];
}

// ---------------------------------------------------------------------------
extern "C" void kernel_launch(void* const* d_in, const int* in_sizes, int n_in,
                              void* d_out, int out_size, void* d_ws,
                              size_t ws_size, hipStream_t stream) {
  const float* x = (const float*)d_in[0];
  const float* pos = (const float*)d_in[1];
  const float* w_qkv = (const float*)d_in[2];
  const float* b_qkv = (const float*)d_in[3];
  const float* w_p1 = (const float*)d_in[4];
  const float* b_p1 = (const float*)d_in[5];
  const float* w_p2 = (const float*)d_in[6];
  const float* b_p2 = (const float*)d_in[7];
  const float* w_a1 = (const float*)d_in[8];
  const float* b_a1 = (const float*)d_in[9];
  const float* w_a2 = (const float*)d_in[10];
  const float* b_a2 = (const float*)d_in[11];
  const float* w_fc = (const float*)d_in[12];
  const float* b_fc = (const float*)d_in[13];
  const float* gamma = (const float*)d_in[14];
  const float* beta = (const float*)d_in[15];

  char* ws = (char*)d_ws;
  float* qkv = (float*)(ws + 0);                        // 6291456 B
  int* knn = (int*)(ws + 6291456);                      // 524288 B
  float* agg = (float*)(ws + 6815744);                  // 2097152 B
  float* y = (float*)(ws + 8912896);                    // 2097152 B
  float* stats = (float*)(ws + 11010048);               // 512 B
  unsigned short* pk1 = (unsigned short*)(ws + 11010560);  // 32768 B
  unsigned short* pk2 = (unsigned short*)(ws + 11043328);  // 32768 B
  unsigned short* pkp = (unsigned short*)(ws + 11076096);  // 8192 B

  hipMemsetAsync(stats, 0, 512, stream);
  hipLaunchKernelGGL(pack_kernel, dim3(144), dim3(256), 0, stream, w_a1, w_a2,
                     w_p2, pk1, pk2, pkp);
  hipLaunchKernelGGL(qkv_kernel, dim3(256), dim3(256), 0, stream, x, w_qkv,
                     b_qkv, qkv);
  hipLaunchKernelGGL(knn_kernel, dim3(2048), dim3(256), 0, stream, pos, knn);
  hipLaunchKernelGGL(attn_kernel, dim3(2048), dim3(256), 0, stream, qkv, pos,
                     knn, pk1, pk2, pkp, w_p1, b_p1, b_p2, b_a1, b_a2, agg);
  hipLaunchKernelGGL(fc_kernel, dim3(128), dim3(256), 0, stream, agg, w_fc,
                     b_fc, y, stats);
  hipLaunchKernelGGL(bn_kernel, dim3(2048), dim3(256), 0, stream, y, x, stats,
                     gamma, beta, (float*)d_out);
}

// Round 6
// 206.050 us; speedup vs baseline: 1.1710x; 1.0821x over previous
//
#include <hip/hip_runtime.h>
#include <hip/hip_bf16.h>
#include <math.h>

#define BN 2
#define NPTS 4096
#define DIM 64
#define HID 256
#define KNB 16
#define CAP 384
#define QPB 8   // knn queries per block

typedef __attribute__((ext_vector_type(8))) short bf16x8;
typedef __attribute__((ext_vector_type(4))) float f32x4;
#define MFMA16(a, b, c) __builtin_amdgcn_mfma_f32_16x16x32_bf16(a, b, c, 0, 0, 0)

__device__ __forceinline__ unsigned short f2bf(float f) {
  unsigned int u = __float_as_uint(f);
  unsigned int r = (u + 0x7fffu + ((u >> 16) & 1u)) >> 16;
  return (unsigned short)r;
}

// ---------------------------------------------------------------------------
// Kernel 1: fused [qkv = x @ w_qkv + b_qkv] (blocks 0..255) +
//           [pack w_a1/w_a2/w_p2 -> bf16 MFMA B-frag order] (blocks 256..399)
// ---------------------------------------------------------------------------
__global__ __launch_bounds__(256) void qkv_pack_kernel(
    const float* __restrict__ x, const float* __restrict__ w,
    const float* __restrict__ b, float* __restrict__ qkv,
    const float* __restrict__ w_a1, const float* __restrict__ w_a2,
    const float* __restrict__ w_p2, unsigned short* __restrict__ pk1,
    unsigned short* __restrict__ pk2, unsigned short* __restrict__ pkp) {
  __shared__ float sw[64 * 192];   // 48 KB
  __shared__ float sx[32 * 64];    // 8 KB
  int tid = threadIdx.x;
  if (blockIdx.x >= 256) {  // pack part
    int e = (blockIdx.x - 256) * 256 + tid;
    if (e < 16384) {  // w_a1 [64][256]: KS=2, NT=16
      int j = e & 7, lane = (e >> 3) & 63, t = e >> 9;
      int ks = t & 1, nt = t >> 1;
      int k = ks * 32 + ((lane >> 4) << 3) + j, n = nt * 16 + (lane & 15);
      pk1[e] = f2bf(w_a1[k * 256 + n]);
    } else if (e < 32768) {  // w_a2 [256][64]: KS=8, NT=4
      int e2 = e - 16384;
      int j = e2 & 7, lane = (e2 >> 3) & 63, t = e2 >> 9;
      int ks = t & 7, nt = t >> 3;
      int k = ks * 32 + ((lane >> 4) << 3) + j, n = nt * 16 + (lane & 15);
      pk2[e2] = f2bf(w_a2[k * 64 + n]);
    } else if (e < 36864) {  // w_p2 [64][64]: KS=2, NT=4
      int e3 = e - 32768;
      int j = e3 & 7, lane = (e3 >> 3) & 63, t = e3 >> 9;
      int ks = t & 1, nt = t >> 1;
      int k = ks * 32 + ((lane >> 4) << 3) + j, n = nt * 16 + (lane & 15);
      pkp[e3] = f2bf(w_p2[k * 64 + n]);
    }
    return;
  }
  int row0 = blockIdx.x * 32;
  for (int o = tid; o < 64 * 192; o += 256) sw[o] = w[o];
  for (int o = tid; o < 32 * 64; o += 256) sx[o] = x[(size_t)row0 * 64 + o];
  __syncthreads();
  for (int o = tid; o < 32 * 192; o += 256) {
    int r = o / 192, c = o % 192;
    float acc = b[c];
    const float* xr = &sx[r * 64];
#pragma unroll
    for (int d = 0; d < 64; ++d) acc = fmaf(xr[d], sw[d * 192 + c], acc);
    qkv[(size_t)(row0 + r) * 192 + c] = acc;
  }
}

// ---------------------------------------------------------------------------
// Kernel 2 (v5): KNN top-16, 8 queries/block, cumulative-threshold count.
//   pass 1: per-thread u32 counters c_f[q] = count(d2 < T_f),
//           T in {0.25, 0.0625, 0.015625, 0.00390625} (bucket edges 4^-1-f).
//   select: shfl+LDS reduce; per query smallest T_f with count >= 16.
//   pass 2: recompute d2 (identical fmaf chain), collect < t* (cap 384).
//   rank select on (d2bits, idx) = reference (dist, idx) tie-break.
//   fallback (count(d2<0.25) < 16, ~impossible for this data): exact
//   iterative min-key-above-prev argmin over recomputed d2.
// ---------------------------------------------------------------------------
__global__ __launch_bounds__(256) void knn_kernel(
    const float* __restrict__ pos, int* __restrict__ knn) {
  __shared__ unsigned int cbits[QPB][CAP];    // 12 KB
  __shared__ int cidx[QPB][CAP];              // 12 KB
  __shared__ unsigned int wredc[4][QPB][4];   // 512 B
  __shared__ unsigned long long wmin[4];
  __shared__ float sthr[QPB];
  __shared__ unsigned int scnt[QPB];
  __shared__ unsigned long long sprev;

  int tid = threadIdx.x, lane = tid & 63, wv = tid >> 6;
  int g0 = blockIdx.x * QPB;      // first global point id (b*4096+i)
  int b = g0 >> 12;
  const float* posb = pos + (size_t)b * NPTS * 3;

  float qx[QPB], qy[QPB], qz[QPB];
#pragma unroll
  for (int q = 0; q < QPB; ++q) {
    int i = (g0 + q) & (NPTS - 1);
    qx[q] = posb[i * 3 + 0];
    qy[q] = posb[i * 3 + 1];
    qz[q] = posb[i * 3 + 2];
  }
  if (tid < QPB) scnt[tid] = 0;

  const float T0 = 0.25f, T1 = 0.0625f, T2 = 0.015625f, T3 = 0.00390625f;
  unsigned int c0[QPB], c1[QPB], c2[QPB], c3[QPB];
#pragma unroll
  for (int q = 0; q < QPB; ++q) { c0[q] = 0; c1[q] = 0; c2[q] = 0; c3[q] = 0; }

  // pass 1: distances + cumulative threshold counts
  for (int c = 0; c < NPTS / 256; ++c) {
    int j3 = (c * 256 + tid) * 3;
    float px = posb[j3 + 0], py = posb[j3 + 1], pz = posb[j3 + 2];
#pragma unroll
    for (int q = 0; q < QPB; ++q) {
      float dx = qx[q] - px, dy = qy[q] - py, dz = qz[q] - pz;
      float d2 = fmaf(dz, dz, fmaf(dy, dy, dx * dx));
      c0[q] += d2 < T0 ? 1u : 0u;
      c1[q] += d2 < T1 ? 1u : 0u;
      c2[q] += d2 < T2 ? 1u : 0u;
      c3[q] += d2 < T3 ? 1u : 0u;
    }
  }

  // reduce counters (wave shfl, then cross-wave in LDS)
#pragma unroll
  for (int q = 0; q < QPB; ++q) {
#pragma unroll
    for (int off = 32; off > 0; off >>= 1) {
      c0[q] += __shfl_down(c0[q], off);
      c1[q] += __shfl_down(c1[q], off);
      c2[q] += __shfl_down(c2[q], off);
      c3[q] += __shfl_down(c3[q], off);
    }
    if (lane == 0) {
      wredc[wv][q][0] = c0[q];
      wredc[wv][q][1] = c1[q];
      wredc[wv][q][2] = c2[q];
      wredc[wv][q][3] = c3[q];
    }
  }
  __syncthreads();
  if (tid < QPB) {
    int q = tid;
    unsigned int s0 = 0, s1 = 0, s2 = 0, s3 = 0;
#pragma unroll
    for (int ww = 0; ww < 4; ++ww) {
      s0 += wredc[ww][q][0];
      s1 += wredc[ww][q][1];
      s2 += wredc[ww][q][2];
      s3 += wredc[ww][q][3];
    }
    float t;
    if (s3 >= KNB) t = T3;
    else if (s2 >= KNB) t = T2;
    else if (s1 >= KNB) t = T1;
    else if (s0 >= KNB) t = T0;
    else t = 1e30f;  // -> collect all -> overflow -> exact fallback
    sthr[q] = t;
  }
  __syncthreads();

  // pass 2: recompute d2, collect candidates below per-query threshold
  float tq[QPB];
#pragma unroll
  for (int q = 0; q < QPB; ++q) tq[q] = sthr[q];
  for (int c = 0; c < NPTS / 256; ++c) {
    int j = c * 256 + tid;
    int j3 = j * 3;
    float px = posb[j3 + 0], py = posb[j3 + 1], pz = posb[j3 + 2];
#pragma unroll
    for (int q = 0; q < QPB; ++q) {
      float dx = qx[q] - px, dy = qy[q] - py, dz = qz[q] - pz;
      float d2 = fmaf(dz, dz, fmaf(dy, dy, dx * dx));
      if (d2 < tq[q]) {
        unsigned int p = atomicAdd(&scnt[q], 1u);
        if (p < CAP) {
          cbits[q][p] = __float_as_uint(d2);
          cidx[q][p] = j;
        }
      }
    }
  }
  __syncthreads();

  // rank selection: wave wv handles queries 2*wv and 2*wv+1
  for (int qq = 0; qq < 2; ++qq) {
    int q = wv * 2 + qq;
    int L = (int)scnt[q];
    if (L <= CAP) {
      for (int i = lane; i < L; i += 64) {
        unsigned long long ki =
            ((unsigned long long)cbits[q][i] << 32) | (unsigned int)cidx[q][i];
        int rank = 0;
        for (int m = 0; m < L; ++m) {
          unsigned long long km = ((unsigned long long)cbits[q][m] << 32) |
                                  (unsigned int)cidx[q][m];
          rank += km < ki;
        }
        if (rank < KNB) knn[(size_t)(g0 + q) * KNB + rank] = cidx[q][i];
      }
    }
  }
  __syncthreads();

  // exact fallback for overflow (block-uniform branch; keys strictly ascend)
  for (int q = 0; q < QPB; ++q) {
    if (scnt[q] > CAP) {
      unsigned long long prev = 0ull;
      for (int r = 0; r < KNB; ++r) {
        unsigned long long best = ~0ull;
        for (int c = 0; c < NPTS / 256; ++c) {
          int j = c * 256 + tid;
          float dx = qx[q] - posb[j * 3 + 0];
          float dy = qy[q] - posb[j * 3 + 1];
          float dz = qz[q] - posb[j * 3 + 2];
          float d2 = fmaf(dz, dz, fmaf(dy, dy, dx * dx));
          unsigned long long key =
              ((unsigned long long)__float_as_uint(d2) << 32) | (unsigned int)j;
          bool ok = (r == 0) || (key > prev);
          best = (ok && key < best) ? key : best;
        }
#pragma unroll
        for (int off = 32; off > 0; off >>= 1) {
          unsigned long long o = __shfl_down(best, off);
          best = best < o ? best : o;
        }
        if (lane == 0) wmin[wv] = best;
        __syncthreads();
        if (tid == 0) {
          unsigned long long m0 = wmin[0], m1 = wmin[1];
          unsigned long long m2 = wmin[2], m3 = wmin[3];
          unsigned long long a = m0 < m1 ? m0 : m1;
          unsigned long long d = m2 < m3 ? m2 : m3;
          a = a < d ? a : d;
          knn[(size_t)(g0 + q) * KNB + r] = (int)(unsigned int)a;
          sprev = a;
        }
        __syncthreads();
        prev = sprev;
        __syncthreads();
      }
    }
  }
}

// ---------------------------------------------------------------------------
// Kernel 3: MFMA attention (unchanged from R3-R5).
// ---------------------------------------------------------------------------
__global__ __launch_bounds__(256) void attn_kernel(
    const float* __restrict__ qkv, const float* __restrict__ pos,
    const int* __restrict__ knn, const unsigned short* __restrict__ pk1,
    const unsigned short* __restrict__ pk2,
    const unsigned short* __restrict__ pkp, const float* __restrict__ w_p1,
    const float* __restrict__ b_p1, const float* __restrict__ b_p2,
    const float* __restrict__ b_a1, const float* __restrict__ b_a2,
    float* __restrict__ aggout) {
  __shared__ __align__(16) char region[33792];
  __shared__ __align__(16) unsigned short s_h[64][72];
  __shared__ float s_v[64][64];
  __shared__ int s_idx[64];

  float(*s_qk)[66] = (float(*)[66])region;
  unsigned short(*s_e)[72] = (unsigned short(*)[72])(region + 16896);
  unsigned short(*s_t)[264] = (unsigned short(*)[264])region;
  float(*s_sc)[66] = (float(*)[66])region;

  int tid = threadIdx.x, w = tid >> 6, lane = tid & 63;
  int g0 = blockIdx.x * 4;
  int b = g0 >> 12;

  if (tid < 64) {
    int p = tid >> 4, k = tid & 15;
    s_idx[tid] = knn[(size_t)(g0 + p) * KNB + k];
  }
  __syncthreads();

  for (int it = 0; it < 16; ++it) {
    int r = it * 4 + w;
    int g = g0 + (r >> 4);
    int jb = (b << 12) | s_idx[r];
    float qv = qkv[(size_t)g * 192 + lane];
    float kv = qkv[(size_t)jb * 192 + 64 + lane];
    float vv = qkv[(size_t)jb * 192 + 128 + lane];
    s_qk[r][lane] = qv - kv;
    s_v[r][lane] = vv;
  }
  {
    float w0 = w_p1[lane], w1 = w_p1[64 + lane], w2 = w_p1[128 + lane];
    float bp = b_p1[lane];
    for (int it = 0; it < 16; ++it) {
      int r = it * 4 + w;
      int g = g0 + (r >> 4);
      int jb = (b << 12) | s_idx[r];
      float rx = pos[(size_t)g * 3 + 0] - pos[(size_t)jb * 3 + 0];
      float ry = pos[(size_t)g * 3 + 1] - pos[(size_t)jb * 3 + 1];
      float rz = pos[(size_t)g * 3 + 2] - pos[(size_t)jb * 3 + 2];
      float e = fmaf(rz, w2, fmaf(ry, w1, fmaf(rx, w0, bp)));
      s_e[r][lane] = f2bf(fmaxf(e, 0.f));
    }
  }
  __syncthreads();

  int m = lane & 15, quad = lane >> 4;
  {
    bf16x8 a0 = *(const bf16x8*)&s_e[16 * w + m][quad * 8];
    bf16x8 a1 = *(const bf16x8*)&s_e[16 * w + m][32 + quad * 8];
#pragma unroll
    for (int nt = 0; nt < 4; ++nt) {
      bf16x8 b0 = *(const bf16x8*)(pkp + ((size_t)(nt * 2 + 0) * 64 + lane) * 8);
      bf16x8 b1 = *(const bf16x8*)(pkp + ((size_t)(nt * 2 + 1) * 64 + lane) * 8);
      f32x4 acc = {0.f, 0.f, 0.f, 0.f};
      acc = MFMA16(a0, b0, acc);
      acc = MFMA16(a1, b1, acc);
      int col = nt * 16 + m;
      float bp2 = b_p2[col];
#pragma unroll
      for (int i = 0; i < 4; ++i) {
        int row = 16 * w + quad * 4 + i;
        float h = s_qk[row][col] + acc[i] + bp2;
        s_h[row][col] = f2bf(h);
      }
    }
  }
  __syncthreads();

  {
    bf16x8 a0 = *(const bf16x8*)&s_h[16 * w + m][quad * 8];
    bf16x8 a1 = *(const bf16x8*)&s_h[16 * w + m][32 + quad * 8];
#pragma unroll 4
    for (int nt = 0; nt < 16; ++nt) {
      bf16x8 b0 = *(const bf16x8*)(pk1 + ((size_t)(nt * 2 + 0) * 64 + lane) * 8);
      bf16x8 b1 = *(const bf16x8*)(pk1 + ((size_t)(nt * 2 + 1) * 64 + lane) * 8);
      f32x4 acc = {0.f, 0.f, 0.f, 0.f};
      acc = MFMA16(a0, b0, acc);
      acc = MFMA16(a1, b1, acc);
      int col = nt * 16 + m;
      float ba = b_a1[col];
#pragma unroll
      for (int i = 0; i < 4; ++i) {
        int row = 16 * w + quad * 4 + i;
        s_t[row][col] = f2bf(fmaxf(acc[i] + ba, 0.f));
      }
    }
  }

  f32x4 acc2[4];
#pragma unroll
  for (int nt = 0; nt < 4; ++nt) acc2[nt] = (f32x4){0.f, 0.f, 0.f, 0.f};
#pragma unroll
  for (int ks = 0; ks < 8; ++ks) {
    bf16x8 a = *(const bf16x8*)&s_t[16 * w + m][ks * 32 + quad * 8];
#pragma unroll
    for (int nt = 0; nt < 4; ++nt) {
      bf16x8 bb = *(const bf16x8*)(pk2 + ((size_t)(nt * 8 + ks) * 64 + lane) * 8);
      acc2[nt] = MFMA16(a, bb, acc2[nt]);
    }
  }
  __syncthreads();
#pragma unroll
  for (int nt = 0; nt < 4; ++nt) {
    int col = nt * 16 + m;
    float ba2 = b_a2[col];
#pragma unroll
    for (int i = 0; i < 4; ++i)
      s_sc[16 * w + quad * 4 + i][col] = acc2[nt][i] + ba2;
  }
  __syncthreads();

  {
    int p = w, d = lane;
    float mx = -1e30f;
#pragma unroll
    for (int k = 0; k < 16; ++k) mx = fmaxf(mx, s_sc[p * 16 + k][d]);
    float s = 0.f, a = 0.f;
#pragma unroll
    for (int k = 0; k < 16; ++k) {
      float e = expf(s_sc[p * 16 + k][d] - mx);
      s += e;
      a = fmaf(e, s_v[p * 16 + k][d], a);
    }
    aggout[(size_t)(g0 + p) * 64 + d] = a / s;
  }
}

// ---------------------------------------------------------------------------
// Kernel 4: y = agg @ w_fc + b_fc; accumulate per-channel sum/sumsq.
// ---------------------------------------------------------------------------
__global__ __launch_bounds__(256) void fc_kernel(
    const float* __restrict__ agg, const float* __restrict__ w_fc,
    const float* __restrict__ b_fc, float* __restrict__ y,
    float* __restrict__ stats) {
  __shared__ float sw[64 * 64];
  __shared__ float sa[64 * 64];
  __shared__ float red[4][64];
  __shared__ float red2[4][64];
  int tid = threadIdx.x;
  int r0 = blockIdx.x * 64;
  for (int o = tid; o < 4096; o += 256) sw[o] = w_fc[o];
  for (int o = tid; o < 4096; o += 256) sa[o] = agg[(size_t)r0 * 64 + o];
  __syncthreads();
  int c = tid & 63, g = tid >> 6;
  float psum = 0.f, psq = 0.f;
  for (int rr = g; rr < 64; rr += 4) {
    float acc = b_fc[c];
#pragma unroll
    for (int d = 0; d < 64; ++d) acc = fmaf(sa[rr * 64 + d], sw[d * 64 + c], acc);
    y[(size_t)(r0 + rr) * 64 + c] = acc;
    psum += acc;
    psq = fmaf(acc, acc, psq);
  }
  red[g][c] = psum;
  red2[g][c] = psq;
  __syncthreads();
  if (tid < 64) {
    float s = red[0][tid] + red[1][tid] + red[2][tid] + red[3][tid];
    float s2 = red2[0][tid] + red2[1][tid] + red2[2][tid] + red2[3][tid];
    atomicAdd(&stats[tid], s);
    atomicAdd(&stats[64 + tid], s2);
  }
}

// ---------------------------------------------------------------------------
// Kernel 5: BN (batch stats) + relu + residual.
// ---------------------------------------------------------------------------
__global__ __launch_bounds__(256) void bn_kernel(
    const float* __restrict__ y, const float* __restrict__ x,
    const float* __restrict__ stats, const float* __restrict__ gamma,
    const float* __restrict__ beta, float* __restrict__ out) {
  size_t o = (size_t)blockIdx.x * 256 + threadIdx.x;
  int c = (int)(o & 63);
  const float inv_n = 1.f / 8192.f;
  float mean = stats[c] * inv_n;
  float var = stats[64 + c] * inv_n - mean * mean;
  float inv = rsqrtf(var + 1e-5f);
  float v = (y[o] - mean) * inv * gamma[c] + beta[c];
  out[o] = fmaxf(v, 0.f) + x[o];
}

// ---------------------------------------------------------------------------
extern "C" void kernel_launch(void* const* d_in, const int* in_sizes, int n_in,
                              void* d_out, int out_size, void* d_ws,
                              size_t ws_size, hipStream_t stream) {
  const float* x = (const float*)d_in[0];
  const float* pos = (const float*)d_in[1];
  const float* w_qkv = (const float*)d_in[2];
  const float* b_qkv = (const float*)d_in[3];
  const float* w_p1 = (const float*)d_in[4];
  const float* b_p1 = (const float*)d_in[5];
  const float* w_p2 = (const float*)d_in[6];
  const float* b_p2 = (const float*)d_in[7];
  const float* w_a1 = (const float*)d_in[8];
  const float* b_a1 = (const float*)d_in[9];
  const float* w_a2 = (const float*)d_in[10];
  const float* b_a2 = (const float*)d_in[11];
  const float* w_fc = (const float*)d_in[12];
  const float* b_fc = (const float*)d_in[13];
  const float* gamma = (const float*)d_in[14];
  const float* beta = (const float*)d_in[15];

  char* ws = (char*)d_ws;
  float* qkv = (float*)(ws + 0);                        // 6291456 B
  int* knn = (int*)(ws + 6291456);                      // 524288 B
  float* agg = (float*)(ws + 6815744);                  // 2097152 B
  float* y = (float*)(ws + 8912896);                    // 2097152 B
  float* stats = (float*)(ws + 11010048);               // 512 B
  unsigned short* pk1 = (unsigned short*)(ws + 11010560);  // 32768 B
  unsigned short* pk2 = (unsigned short*)(ws + 11043328);  // 32768 B
  unsigned short* pkp = (unsigned short*)(ws + 11076096);  // 8192 B

  hipMemsetAsync(stats, 0, 512, stream);
  hipLaunchKernelGGL(qkv_pack_kernel, dim3(400), dim3(256), 0, stream, x,
                     w_qkv, b_qkv, qkv, w_a1, w_a2, w_p2, pk1, pk2, pkp);
  hipLaunchKernelGGL(knn_kernel, dim3(1024), dim3(256), 0, stream, pos, knn);
  hipLaunchKernelGGL(attn_kernel, dim3(2048), dim3(256), 0, stream, qkv, pos,
                     knn, pk1, pk2, pkp, w_p1, b_p1, b_p2, b_a1, b_a2, agg);
  hipLaunchKernelGGL(fc_kernel, dim3(128), dim3(256), 0, stream, agg, w_fc,
                     b_fc, y, stats);
  hipLaunchKernelGGL(bn_kernel, dim3(2048), dim3(256), 0, stream, y, x, stats,
                     gamma, beta, (float*)d_out);
}